// Round 1
// baseline (82.519 us; speedup 1.0000x reference)
//
#include <hip/hip_runtime.h>

#define NT 2048          // number of distinct event times
#define NB 256           // histogram blocks (per-block partials)
#define HIST_TPB 1024
#define TPB 256

// ---------------------------------------------------------------------------
// Kernel 1: per-block histogram of exp(hr), exp(hr)*e, count(e) over time bins
// plus per-block sums of hr*e and e. Deterministic per-block partials in ws.
// ---------------------------------------------------------------------------
__global__ __launch_bounds__(HIST_TPB) void hist_kernel(
    const float* __restrict__ hr, const int* __restrict__ dur,
    const int* __restrict__ ev, int n,
    double* __restrict__ s_part, double* __restrict__ T_part,
    unsigned* __restrict__ n_part,
    double* __restrict__ hrE_part, double* __restrict__ eCnt_part)
{
    __shared__ float s_loc[NT];
    __shared__ float T_loc[NT];
    __shared__ unsigned n_loc[NT];
    __shared__ double redH[HIST_TPB / 64];
    __shared__ double redC[HIST_TPB / 64];

    for (int i = threadIdx.x; i < NT; i += HIST_TPB) {
        s_loc[i] = 0.f; T_loc[i] = 0.f; n_loc[i] = 0u;
    }
    __syncthreads();

    double hrE = 0.0;
    double ec  = 0.0;
    int stride = gridDim.x * HIST_TPB;
    for (int i = blockIdx.x * HIST_TPB + threadIdx.x; i < n; i += stride) {
        float h = hr[i];
        int   d = dur[i];
        int   e = ev[i];
        float eh = expf(h);
        atomicAdd(&s_loc[d], eh);
        if (e) {
            atomicAdd(&T_loc[d], eh);
            atomicAdd(&n_loc[d], 1u);
            hrE += (double)h;
            ec  += 1.0;
        }
    }
    __syncthreads();

    size_t base = (size_t)blockIdx.x * NT;
    for (int i = threadIdx.x; i < NT; i += HIST_TPB) {
        s_part[base + i] = (double)s_loc[i];
        T_part[base + i] = (double)T_loc[i];
        n_part[base + i] = n_loc[i];
    }

    // block-reduce hrE / ec (wave shuffle + LDS across waves)
    for (int o = 32; o > 0; o >>= 1) {
        hrE += __shfl_down(hrE, o, 64);
        ec  += __shfl_down(ec,  o, 64);
    }
    int wave = threadIdx.x >> 6;
    if ((threadIdx.x & 63) == 0) { redH[wave] = hrE; redC[wave] = ec; }
    __syncthreads();
    if (threadIdx.x == 0) {
        double h = 0.0, c = 0.0;
        for (int w = 0; w < HIST_TPB / 64; ++w) { h += redH[w]; c += redC[w]; }
        hrE_part[blockIdx.x]  = h;
        eCnt_part[blockIdx.x] = c;
    }
}

// ---------------------------------------------------------------------------
// Kernel 2: reduce per-block partials -> final s[t], T[t], n[t] (fp64)
// ---------------------------------------------------------------------------
__global__ __launch_bounds__(TPB) void reduce_kernel(
    const double* __restrict__ s_part, const double* __restrict__ T_part,
    const unsigned* __restrict__ n_part,
    double* __restrict__ s_fin, double* __restrict__ T_fin,
    unsigned* __restrict__ n_fin)
{
    int t = blockIdx.x * TPB + threadIdx.x;   // NT/TPB blocks
    double s = 0.0, T = 0.0;
    unsigned c = 0u;
    for (int b = 0; b < NB; ++b) {
        size_t idx = (size_t)b * NT + t;
        s += s_part[idx];
        T += T_part[idx];
        c += n_part[idx];
    }
    s_fin[t] = s;
    T_fin[t] = T;
    n_fin[t] = c;
}

// ---------------------------------------------------------------------------
// Kernel 3: suffix cumsum R[t] = sum_{t'>=t} s[t']  (1 block, LDS scan)
// ---------------------------------------------------------------------------
__global__ __launch_bounds__(1024) void scan_kernel(
    const double* __restrict__ s_fin, double* __restrict__ R)
{
    __shared__ double b0[NT];
    __shared__ double b1[NT];
    double* cur = b0;
    double* nxt = b1;
    for (int i = threadIdx.x; i < NT; i += 1024) b0[i] = s_fin[i];
    __syncthreads();
    for (int off = 1; off < NT; off <<= 1) {
        for (int i = threadIdx.x; i < NT; i += 1024) {
            double v = cur[i];
            if (i + off < NT) v += cur[i + off];
            nxt[i] = v;
        }
        __syncthreads();
        double* tmp = cur; cur = nxt; nxt = tmp;
    }
    for (int i = threadIdx.x; i < NT; i += 1024) R[i] = cur[i];
}

// ---------------------------------------------------------------------------
// Kernel 4: Efron correction per time t:
//   corr_part[t] = sum_{k=0}^{n_t-1} log(R[t] - (k/n_t)*T[t])
// ---------------------------------------------------------------------------
__global__ __launch_bounds__(TPB) void efron_kernel(
    const double* __restrict__ R, const double* __restrict__ T_fin,
    const unsigned* __restrict__ n_fin, double* __restrict__ corr_part)
{
    __shared__ double red[TPB / 64];
    int t = blockIdx.x;
    unsigned nt = n_fin[t];
    double acc = 0.0;
    if (nt > 0) {
        double Rt = R[t];
        double Tt = T_fin[t];
        double inv_n = 1.0 / (double)nt;
        for (unsigned k = threadIdx.x; k < nt; k += TPB) {
            acc += log(Rt - ((double)k * inv_n) * Tt);
        }
    }
    for (int o = 32; o > 0; o >>= 1) acc += __shfl_down(acc, o, 64);
    int wave = threadIdx.x >> 6;
    if ((threadIdx.x & 63) == 0) red[wave] = acc;
    __syncthreads();
    if (threadIdx.x == 0) {
        double s = 0.0;
        for (int w = 0; w < TPB / 64; ++w) s += red[w];
        corr_part[t] = s;
    }
}

// ---------------------------------------------------------------------------
// Kernel 5: final reduction and loss
// ---------------------------------------------------------------------------
__global__ __launch_bounds__(1024) void final_kernel(
    const double* __restrict__ corr_part, const double* __restrict__ hrE_part,
    const double* __restrict__ eCnt_part, float* __restrict__ out)
{
    __shared__ double redA[1024 / 64];
    __shared__ double redB[1024 / 64];
    __shared__ double redC[1024 / 64];

    double a = 0.0;
    for (int i = threadIdx.x; i < NT; i += 1024) a += corr_part[i];
    double h = 0.0, c = 0.0;
    if (threadIdx.x < NB) {
        h = hrE_part[threadIdx.x];
        c = eCnt_part[threadIdx.x];
    }
    for (int o = 32; o > 0; o >>= 1) {
        a += __shfl_down(a, o, 64);
        h += __shfl_down(h, o, 64);
        c += __shfl_down(c, o, 64);
    }
    int wave = threadIdx.x >> 6;
    if ((threadIdx.x & 63) == 0) { redA[wave] = a; redB[wave] = h; redC[wave] = c; }
    __syncthreads();
    if (threadIdx.x == 0) {
        double corr = 0.0, hrE = 0.0, ec = 0.0;
        for (int w = 0; w < 1024 / 64; ++w) {
            corr += redA[w]; hrE += redB[w]; ec += redC[w];
        }
        double loss = hrE - corr;
        out[0] = (float)(-loss / (ec + 1e-7));
    }
}

// ---------------------------------------------------------------------------
extern "C" void kernel_launch(void* const* d_in, const int* in_sizes, int n_in,
                              void* d_out, int out_size, void* d_ws, size_t ws_size,
                              hipStream_t stream)
{
    const float* hr  = (const float*)d_in[0];
    const int*   dur = (const int*)d_in[1];
    const int*   ev  = (const int*)d_in[2];
    int n = in_sizes[1];

    // workspace layout (all deterministically overwritten each call)
    char* ws = (char*)d_ws;
    double*   s_part    = (double*)ws;                         // NB*NT doubles (4 MB)
    double*   T_part    = s_part + (size_t)NB * NT;            // 4 MB
    unsigned* n_part    = (unsigned*)(T_part + (size_t)NB * NT); // 2 MB
    double*   s_fin     = (double*)(n_part + (size_t)NB * NT); // 16 KB
    double*   T_fin     = s_fin + NT;
    double*   R         = T_fin + NT;
    unsigned* n_fin     = (unsigned*)(R + NT);                 // 8 KB
    double*   corr_part = (double*)(n_fin + NT);               // 16 KB
    double*   hrE_part  = corr_part + NT;                      // 2 KB
    double*   eCnt_part = hrE_part + NB;                       // 2 KB

    hipLaunchKernelGGL(hist_kernel, dim3(NB), dim3(HIST_TPB), 0, stream,
                       hr, dur, ev, n, s_part, T_part, n_part, hrE_part, eCnt_part);
    hipLaunchKernelGGL(reduce_kernel, dim3(NT / TPB), dim3(TPB), 0, stream,
                       s_part, T_part, n_part, s_fin, T_fin, n_fin);
    hipLaunchKernelGGL(scan_kernel, dim3(1), dim3(1024), 0, stream, s_fin, R);
    hipLaunchKernelGGL(efron_kernel, dim3(NT), dim3(TPB), 0, stream,
                       R, T_fin, n_fin, corr_part);
    hipLaunchKernelGGL(final_kernel, dim3(1), dim3(1024), 0, stream,
                       corr_part, hrE_part, eCnt_part, (float*)d_out);
}